// Round 7
// baseline (397.285 us; speedup 1.0000x reference)
//
#include <hip/hip_runtime.h>
#include <hip/hip_bf16.h>

// Problem constants (from reference)
#define BATCH 16384
#define DIM   128
#define HID   1024
#define NK    8
#define OPD   25          // 3*K+1
#define N3    (DIM*OPD)   // 3200
#define NP    3328        // 26 tiles x 128 cols; tile = 5 dims x 25 params + 3 pad

typedef __attribute__((ext_vector_type(8))) short  short8;   // 8 bf16 (4 VGPRs)
typedef __attribute__((ext_vector_type(4))) float  floatx4;  // MFMA C/D frag
typedef unsigned int u32;

// async global->LDS, 16B per lane. dst = wave-uniform base + lane*16.
__device__ __forceinline__ void async_copy16(const unsigned short* g,
                                             unsigned short* l) {
    __builtin_amdgcn_global_load_lds(
        (const __attribute__((address_space(1))) u32*)g,
        (__attribute__((address_space(3))) u32*)l,
        16, 0, 0);
}

// ---------------------------------------------------------------- prep kernels
__global__ void cvt_bf16_kernel(const float* __restrict__ in,
                                __hip_bfloat16* __restrict__ out, int n) {
    int i = blockIdx.x * blockDim.x + threadIdx.x;
    if (i < n) out[i] = __float2bfloat16(in[i]);
}

__global__ void lad_init_kernel(float* __restrict__ lad) {
    lad[blockIdx.x * 256 + threadIdx.x] = 0.f;
}

// Recover h1/h2 from masks, counting-sort hidden units (layer1 by h1, layer2
// by h2), and compute per-N-tile K prefix bounds (rounded up to BK=64).
// Masks are prefix-structured: m1[h,i]=(i<h1[h]), m2[i,j]=(h1[j]<=h2[i]),
// m3[d*OPD+k, j]=(h2[j]<=d). Skipped K-region is exact zeros -> bit-identical.
__global__ __launch_bounds__(1024) void build_perm_kernel(
    const float* __restrict__ m1, const float* __restrict__ m3,
    int* __restrict__ perm1, int* __restrict__ perm2,
    int* __restrict__ klim1, int* __restrict__ klim2, int* __restrict__ klim3)
{
    __shared__ int hist[128];
    __shared__ int h1s[1024], h2s[1024];
    const int t = threadIdx.x;

    float s1 = 0.f;
    for (int i = 0; i < DIM; i++) s1 += m1[t * DIM + i];
    const int h1v = (int)(s1 + 0.5f);                 // = h1[t] in [1,127]

    float s2 = 0.f;
    for (int d = 0; d < DIM; d++) s2 += m3[(size_t)d * OPD * HID + t];
    const int h2v = DIM - (int)(s2 + 0.5f);           // = h2[t] in [1,127]

    // counting sort by h1 -> perm1, h1s
    if (t < 128) hist[t] = 0;
    __syncthreads();
    atomicAdd(&hist[h1v], 1);
    __syncthreads();
    if (t == 0) { int a = 0; for (int b = 0; b < 128; b++) { int c = hist[b]; hist[b] = a; a += c; } }
    __syncthreads();
    int r = atomicAdd(&hist[h1v], 1);
    perm1[r] = t; h1s[r] = h1v;
    __syncthreads();
    // counting sort by h2 -> perm2, h2s
    if (t < 128) hist[t] = 0;
    __syncthreads();
    atomicAdd(&hist[h2v], 1);
    __syncthreads();
    if (t == 0) { int a = 0; for (int b = 0; b < 128; b++) { int c = hist[b]; hist[b] = a; a += c; } }
    __syncthreads();
    r = atomicAdd(&hist[h2v], 1);
    perm2[r] = t; h2s[r] = h2v;
    __syncthreads();

    if (t < 8) {
        // GEMM1: active cols for unit with value v = v  -> Klim = round64(max v)
        int mx = h1s[t * 128 + 127];
        klim1[t] = ((mx + 63) >> 6) << 6;
        // GEMM2: Klim = round64(#{j: h1s[j] <= max h2 in tile})
        int mh = h2s[t * 128 + 127];
        int c = 0;
        for (int j = 0; j < 1024; j++) c += (h1s[j] <= mh) ? 1 : 0;
        klim2[t] = ((c + 63) >> 6) << 6;
    }
    if (t < 26) {
        // GEMM3: tile t covers dims t*5..t*5+4; active j: h2[j] <= dmax
        int dmax = t * 5 + 4; if (dmax > 127) dmax = 127;
        int c = 0;
        for (int j = 0; j < 1024; j++) c += (h2s[j] <= dmax) ? 1 : 0;
        klim3[t] = ((c + 63) >> 6) << 6;
    }
}

// w1p[h',i] = (W1*m1)[perm1[h'], i]; b1p[h'] = b1[perm1[h']]
__global__ void w1_perm_kernel(const float* __restrict__ W1,
                               const float* __restrict__ m1,
                               const float* __restrict__ b1,
                               const int* __restrict__ perm1,
                               __hip_bfloat16* __restrict__ w1p,
                               float* __restrict__ b1p) {
    int i = blockIdx.x * blockDim.x + threadIdx.x;   // HID*DIM
    int hp = i >> 7, col = i & 127;
    int src = perm1[hp];
    w1p[i] = __float2bfloat16(W1[src * DIM + col] * m1[src * DIM + col]);
    if (col == 0) b1p[hp] = b1[src];
}

// w2p[i',j'] = (W2*m2)[perm2[i'], perm1[j']]; b2p[i'] = b2[perm2[i']]
__global__ void w2_perm_kernel(const float* __restrict__ W2,
                               const float* __restrict__ m2,
                               const float* __restrict__ b2,
                               const int* __restrict__ perm1,
                               const int* __restrict__ perm2,
                               __hip_bfloat16* __restrict__ w2p,
                               float* __restrict__ b2p) {
    int i = blockIdx.x * blockDim.x + threadIdx.x;   // HID*HID
    int ip = i >> 10, jp = i & 1023;
    int si = perm2[ip], sj = perm1[jp];
    size_t s = (size_t)si * HID + sj;                // gather within one 4KB row
    w2p[i] = __float2bfloat16(W2[s] * m2[s]);
    if (jp == 0) b2p[ip] = b2[si];
}

// w3p: padded col c=t*128+s <-> source col t*125+s (s<125); K gathered by perm2
__global__ void w3_perm_kernel(const float* __restrict__ W3,
                               const float* __restrict__ m3,
                               const int* __restrict__ perm2,
                               __hip_bfloat16* __restrict__ w3p) {
    int i = blockIdx.x * blockDim.x + threadIdx.x;   // NP*HID
    int c = i >> 10, kk = i & 1023;
    int s = c & 127, t = c >> 7;
    float v = 0.f;
    if (s < 125) {
        size_t idx = (size_t)(t * 125 + s) * HID + perm2[kk];
        v = W3[idx] * m3[idx];
    }
    w3p[i] = __float2bfloat16(v);
}

// ---------------------------------------------------------------- spline eval
// p[0..7]=uw, p[8..15]=uh, p[16..24]=ud. Softplus only on the 2 selected
// params; selection on unnormalized cumsums. Verified rounds 2-6.
__device__ __forceinline__ void spline_eval(const float* __restrict__ p,
                                            float xv, float& yout, float& lout) {
    float cw[NK + 1], ch[NK + 1];
    {
        float mx = p[0];
        #pragma unroll
        for (int j = 1; j < NK; j++) mx = fmaxf(mx, p[j]);
        float e[NK], s = 0.f;
        #pragma unroll
        for (int j = 0; j < NK; j++) { e[j] = expf(p[j] - mx); s += e[j]; }
        const float inv = 1.f / s;
        cw[0] = 0.f;
        #pragma unroll
        for (int j = 0; j < NK; j++) cw[j + 1] = cw[j] + (0.001f + 0.992f * e[j] * inv);
    }
    {
        float mx = p[8];
        #pragma unroll
        for (int j = 1; j < NK; j++) mx = fmaxf(mx, p[8 + j]);
        float e[NK], s = 0.f;
        #pragma unroll
        for (int j = 0; j < NK; j++) { e[j] = expf(p[8 + j] - mx); s += e[j]; }
        const float inv = 1.f / s;
        ch[0] = 0.f;
        #pragma unroll
        for (int j = 0; j < NK; j++) ch[j + 1] = ch[j] + (0.001f + 0.992f * e[j] * inv);
    }
    const float icw = 1.f / fmaxf(cw[NK], 1e-12f);
    const float ich = 1.f / fmaxf(ch[NK], 1e-12f);

    const bool inside = (xv >= -3.f) && (xv <= 3.f);
    float xs = (xv + 3.f) * (1.f / 6.f);
    xs = fminf(fmaxf(xs, 0.f), 1.f);
    const float xsc = xs * cw[NK];          // compare in unnormalized domain

    float xk = 0.f, wk = cw[1], yk = 0.f, hk = ch[1];
    float uda = p[16], udb = p[17];
    #pragma unroll
    for (int j = 1; j < NK; j++) {
        const bool c = (xsc >= cw[j]);
        xk  = c ? cw[j] : xk;
        wk  = c ? (cw[j + 1] - cw[j]) : wk;
        yk  = c ? ch[j] : yk;
        hk  = c ? (ch[j + 1] - ch[j]) : hk;
        uda = c ? p[16 + j] : uda;
        udb = c ? p[17 + j] : udb;
    }
    xk *= icw; wk *= icw;
    yk *= ich; hk *= ich;

    const float dk  = 0.001f + ((uda > 20.f) ? uda : log1pf(expf(uda)));
    const float dk1 = 0.001f + ((udb > 20.f) ? udb : log1pf(expf(udb)));

    float t = (xs - xk) / (wk + 1e-12f);
    t = fminf(fmaxf(t, 0.f), 1.f);
    const float a   = (hk + 1e-12f) / (wk + 1e-12f);
    const float omt = 1.f - t;
    const float tt1 = t * omt;
    const float num = a * t * t + dk * tt1;
    const float den = a + (dk + dk1 - 2.f * a) * tt1;
    const float s   = num / (den + 1e-12f);
    const float y   = (yk + hk * s) * 6.f - 3.f;
    const float dnum = a * a * (dk1 * t * t + 2.f * a * tt1 + dk * omt * omt);
    const float dydx = dnum / (den * den + 1e-12f);

    yout = inside ? y : xv;
    lout = inside ? logf(fmaxf(dydx, 1e-12f)) : 0.f;
}

// ---------------------------------------------------------------- GEMM (1,2)
// C[M,N] = A[M,K] * Bw[N,K]^T + bias, silu -> bf16. Per-tile K bound klim
// (sorted-mask prefix). Proven staging: global_load_lds w=16 + XOR swizzle.
__global__ __launch_bounds__(256) void gemm_bt_kernel(
    const unsigned short* __restrict__ A,
    const unsigned short* __restrict__ Bw,
    const float* __restrict__ bias,
    const int* __restrict__ klim,
    __hip_bfloat16* __restrict__ Cout,
    int M, int N, int Kd)
{
    constexpr int BM = 128, BN = 128, BK = 64;
    __shared__ unsigned short As[BM * BK];
    __shared__ unsigned short Bs[BN * BK];

    const int bid = blockIdx.y * gridDim.x + blockIdx.x;
    const int GY  = (gridDim.y >= 16) ? 16 : gridDim.y;
    const int per_group = gridDim.x * GY;
    const int g  = bid / per_group;
    const int rr = bid % per_group;
    const int bn = (rr / GY) * BN;
    const int bm = (g * GY + (rr % GY)) * BM;
    const int Klim = klim[bn >> 7];

    const int t    = threadIdx.x;
    const int lane = t & 63;
    const int w    = t >> 6;
    const int wr   = (w >> 1) * 64;
    const int wc   = (w & 1) * 64;
    const int lr   = lane & 15;
    const int quad = lane >> 4;
    const int lxor = lr & 7;

    floatx4 acc[4][4] = {};

    const int lrow = lane >> 3;
    const int lcol = ((lane & 7) ^ lrow) * 8;

    for (int k0 = 0; k0 < Klim; k0 += BK) {
        __syncthreads();
        #pragma unroll
        for (int p = 0; p < 4; p++) {
            const int q = w * 4 + p;
            const int r = q * 8 + lrow;
            async_copy16(&A[(size_t)(bm + r) * Kd + k0 + lcol],
                         &As[q * 512 + lane * 8]);
            async_copy16(&Bw[(size_t)(bn + r) * Kd + k0 + lcol],
                         &Bs[q * 512 + lane * 8]);
        }
        __syncthreads();
        #pragma unroll
        for (int ks = 0; ks < BK; ks += 32) {
            const int cbase = (ks >> 3) + quad;
            const int coff  = (cbase ^ lxor) * 8;
            short8 af[4], bfr[4];
            #pragma unroll
            for (int i = 0; i < 4; i++)
                af[i] = *(const short8*)&As[(wr + i * 16 + lr) * BK + coff];
            #pragma unroll
            for (int j = 0; j < 4; j++)
                bfr[j] = *(const short8*)&Bs[(wc + j * 16 + lr) * BK + coff];
            #pragma unroll
            for (int i = 0; i < 4; i++)
                #pragma unroll
                for (int j = 0; j < 4; j++)
                    acc[i][j] = __builtin_amdgcn_mfma_f32_16x16x32_bf16(
                        af[i], bfr[j], acc[i][j], 0, 0, 0);
        }
    }

    #pragma unroll
    for (int j = 0; j < 4; j++) {
        const int col = bn + wc + j * 16 + lr;
        const float bv = bias[col];
        #pragma unroll
        for (int i = 0; i < 4; i++) {
            const int rowb = bm + wr + i * 16 + quad * 4;
            #pragma unroll
            for (int r = 0; r < 4; r++) {
                float v = acc[i][j][r] + bv;
                v = v / (1.f + expf(-v));
                Cout[(size_t)(rowb + r) * N + col] = __float2bfloat16(v);
            }
        }
    }
}

// ---------------------------------------------------------------- GEMM3+spline
__global__ __launch_bounds__(256) void gemm3_spline_kernel(
    const unsigned short* __restrict__ A,    // h2b M x HID (perm2 col order)
    const unsigned short* __restrict__ Bw,   // w3p NP x HID (perm2 col order)
    const float* __restrict__ b3,            // N3 (original layout)
    const int* __restrict__ klim,            // [26]
    const float* __restrict__ x,             // M x DIM fp32
    float* __restrict__ out,                 // M x DIM
    float* __restrict__ lad,                 // M, pre-zeroed
    int M)
{
    constexpr int BM = 128, BN = 128, BK = 64, Kd = HID;
    constexpr int LSE = 133;                          // epilogue stride
    __shared__ __align__(16) char smem[64 * LSE * 4 + 128 * 4]; // 34,560 B
    unsigned short* As = (unsigned short*)smem;       // 16 KB
    unsigned short* Bs = (unsigned short*)(smem + BM * BK * 2);
    float* eb     = (float*)smem;
    float* ladacc = (float*)(smem + 64 * LSE * 4);    // [128]

    const int bid = blockIdx.y * gridDim.x + blockIdx.x;
    const int GY  = 16;                               // gridDim.y = 128
    const int per_group = gridDim.x * GY;
    const int g  = bid / per_group;
    const int rr = bid % per_group;
    const int tile = rr / GY;                         // 0..25
    const int bn = tile * BN;
    const int bm = (g * GY + (rr % GY)) * BM;
    const int Klim = klim[tile];

    const int t    = threadIdx.x;
    const int lane = t & 63;
    const int w    = t >> 6;
    const int wr   = (w >> 1) * 64;
    const int wc   = (w & 1) * 64;
    const int lr   = lane & 15;
    const int quad = lane >> 4;
    const int lxor = lr & 7;

    if (t < 128) ladacc[t] = 0.f;

    floatx4 acc[4][4] = {};

    const int lrow = lane >> 3;
    const int lcol = ((lane & 7) ^ lrow) * 8;

    for (int k0 = 0; k0 < Klim; k0 += BK) {
        __syncthreads();
        #pragma unroll
        for (int p = 0; p < 4; p++) {
            const int q = w * 4 + p;
            const int r = q * 8 + lrow;
            async_copy16(&A[(size_t)(bm + r) * Kd + k0 + lcol],
                         &As[q * 512 + lane * 8]);
            async_copy16(&Bw[(size_t)(bn + r) * Kd + k0 + lcol],
                         &Bs[q * 512 + lane * 8]);
        }
        __syncthreads();
        #pragma unroll
        for (int ks = 0; ks < BK; ks += 32) {
            const int cbase = (ks >> 3) + quad;
            const int coff  = (cbase ^ lxor) * 8;
            short8 af[4], bfr[4];
            #pragma unroll
            for (int i = 0; i < 4; i++)
                af[i] = *(const short8*)&As[(wr + i * 16 + lr) * BK + coff];
            #pragma unroll
            for (int j = 0; j < 4; j++)
                bfr[j] = *(const short8*)&Bs[(wc + j * 16 + lr) * BK + coff];
            #pragma unroll
            for (int i = 0; i < 4; i++)
                #pragma unroll
                for (int j = 0; j < 4; j++)
                    acc[i][j] = __builtin_amdgcn_mfma_f32_16x16x32_bf16(
                        af[i], bfr[j], acc[i][j], 0, 0, 0);
        }
    }

    // ---- fused epilogue: two 64-row halves ----
    #pragma unroll 1
    for (int h = 0; h < 2; h++) {
        __syncthreads();
        if ((w >> 1) == h) {
            #pragma unroll
            for (int j = 0; j < 4; j++) {
                const int s = wc + j * 16 + lr;
                const float bv = (s < 125) ? b3[tile * 125 + s] : 0.f;
                #pragma unroll
                for (int i = 0; i < 4; i++) {
                    const int lrw = i * 16 + quad * 4;
                    #pragma unroll
                    for (int r2 = 0; r2 < 4; r2++)
                        eb[(lrw + r2) * LSE + s] = acc[i][j][r2] + bv;
                }
            }
        }
        __syncthreads();
        #pragma unroll 1
        for (int q = t; q < 320; q += 256) {
            const int r  = q / 5;
            const int ds = q % 5;
            const int dim = tile * 5 + ds;
            if (dim < DIM) {
                const float* p = eb + r * LSE + ds * 25;
                const int grow = bm + h * 64 + r;
                const float xv = x[(size_t)grow * DIM + dim];
                float y, l;
                spline_eval(p, xv, y, l);
                out[(size_t)grow * DIM + dim] = y;
                atomicAdd(&ladacc[h * 64 + r], l);
            }
        }
    }
    __syncthreads();
    if (t < 128) atomicAdd(&lad[bm + t], ladacc[t]);
}

// ---------------------------------------------------------------- launch
extern "C" void kernel_launch(void* const* d_in, const int* in_sizes, int n_in,
                              void* d_out, int out_size, void* d_ws, size_t ws_size,
                              hipStream_t stream) {
    const float* x  = (const float*)d_in[0];
    const float* W1 = (const float*)d_in[1];
    const float* b1 = (const float*)d_in[2];
    const float* W2 = (const float*)d_in[3];
    const float* b2 = (const float*)d_in[4];
    const float* W3 = (const float*)d_in[5];
    const float* b3 = (const float*)d_in[6];
    const float* m1 = (const float*)d_in[7];
    const float* m2 = (const float*)d_in[8];
    const float* m3 = (const float*)d_in[9];

    // workspace: ~81 MB + small int/bias arrays
    char* ws = (char*)d_ws;
    const size_t OFF_W1B = 0;
    const size_t OFF_W2B = OFF_W1B + (size_t)HID * DIM * 2;
    const size_t OFF_W3P = OFF_W2B + (size_t)HID * HID * 2;
    const size_t OFF_XB  = OFF_W3P + (size_t)NP * HID * 2;
    const size_t OFF_H1B = OFF_XB  + (size_t)BATCH * DIM * 2;
    const size_t OFF_H2B = OFF_H1B + (size_t)BATCH * HID * 2;
    const size_t OFF_SML = OFF_H2B + (size_t)BATCH * HID * 2;

    __hip_bfloat16* w1p = (__hip_bfloat16*)(ws + OFF_W1B);
    __hip_bfloat16* w2p = (__hip_bfloat16*)(ws + OFF_W2B);
    __hip_bfloat16* w3p = (__hip_bfloat16*)(ws + OFF_W3P);
    __hip_bfloat16* xb  = (__hip_bfloat16*)(ws + OFF_XB);
    __hip_bfloat16* h1b = (__hip_bfloat16*)(ws + OFF_H1B);
    __hip_bfloat16* h2b = (__hip_bfloat16*)(ws + OFF_H2B);

    float* b1p   = (float*)(ws + OFF_SML);
    float* b2p   = b1p + HID;
    int*   perm1 = (int*)(b2p + HID);
    int*   perm2 = perm1 + HID;
    int*   klim1 = perm2 + HID;
    int*   klim2 = klim1 + 8;
    int*   klim3 = klim2 + 8;

    float* out_p = (float*)d_out;
    float* lad_p = out_p + (size_t)BATCH * DIM;

    // prep
    build_perm_kernel<<<1, 1024, 0, stream>>>(m1, m3, perm1, perm2,
                                              klim1, klim2, klim3);
    w1_perm_kernel<<<(HID * DIM) / 256, 256, 0, stream>>>(W1, m1, b1, perm1, w1p, b1p);
    w2_perm_kernel<<<(HID * HID) / 256, 256, 0, stream>>>(W2, m2, b2, perm1, perm2, w2p, b2p);
    w3_perm_kernel<<<((size_t)NP * HID) / 256, 256, 0, stream>>>(W3, m3, perm2, w3p);
    cvt_bf16_kernel<<<(BATCH * DIM) / 256, 256, 0, stream>>>(x, xb, BATCH * DIM);
    lad_init_kernel<<<BATCH / 256, 256, 0, stream>>>(lad_p);

    // GEMMs (per-tile K bounds from sorted-mask prefixes)
    gemm_bt_kernel<<<dim3(HID / 128, BATCH / 128), 256, 0, stream>>>(
        (const unsigned short*)xb, (const unsigned short*)w1p, b1p, klim1, h1b,
        BATCH, HID, DIM);
    gemm_bt_kernel<<<dim3(HID / 128, BATCH / 128), 256, 0, stream>>>(
        (const unsigned short*)h1b, (const unsigned short*)w2p, b2p, klim2, h2b,
        BATCH, HID, HID);
    gemm3_spline_kernel<<<dim3(NP / 128, BATCH / 128), 256, 0, stream>>>(
        (const unsigned short*)h2b, (const unsigned short*)w3p, b3, klim3, x,
        out_p, lad_p, BATCH);
}

// Round 8
// 359.317 us; speedup vs baseline: 1.1057x; 1.1057x over previous
//
#include <hip/hip_runtime.h>
#include <hip/hip_bf16.h>

// Problem constants (from reference)
#define BATCH 16384
#define DIM   128
#define HID   1024
#define NK    8
#define OPD   25          // 3*K+1
#define N3    (DIM*OPD)   // 3200
#define NP    3328        // 26 tiles x 128 cols; tile = 5 dims x 25 params + 3 pad

typedef __attribute__((ext_vector_type(8))) short  short8;   // 8 bf16 (4 VGPRs)
typedef __attribute__((ext_vector_type(4))) float  floatx4;  // MFMA C/D frag
typedef unsigned int u32;

// async global->LDS, 16B per lane. dst = wave-uniform base + lane*16.
__device__ __forceinline__ void async_copy16(const unsigned short* g,
                                             unsigned short* l) {
    __builtin_amdgcn_global_load_lds(
        (const __attribute__((address_space(1))) u32*)g,
        (__attribute__((address_space(3))) u32*)l,
        16, 0, 0);
}

// ---------------------------------------------------------------- prep kernels
__global__ void cvt_bf16_kernel(const float* __restrict__ in,
                                __hip_bfloat16* __restrict__ out, int n) {
    int i = blockIdx.x * blockDim.x + threadIdx.x;
    if (i < n) out[i] = __float2bfloat16(in[i]);
}

__global__ void lad_init_kernel(float* __restrict__ lad) {
    lad[blockIdx.x * 256 + threadIdx.x] = 0.f;
}

// h1[r] = sum_i m1[r][i]  (coalesced row-reduce, one block per row)
__global__ __launch_bounds__(128) void h1_sum_kernel(
    const float* __restrict__ m1, int* __restrict__ h1i) {
    const int r = blockIdx.x, t = threadIdx.x;
    float v = m1[r * DIM + t];
    #pragma unroll
    for (int off = 32; off > 0; off >>= 1) v += __shfl_down(v, off, 64);
    __shared__ float ws[2];
    if ((t & 63) == 0) ws[t >> 6] = v;
    __syncthreads();
    if (t == 0) h1i[r] = (int)(ws[0] + ws[1] + 0.5f);
}

// h2[j] = 128 - sum_d m3[d*OPD][j]  (coalesced column sums)
__global__ __launch_bounds__(256) void h2_sum_kernel(
    const float* __restrict__ m3, int* __restrict__ h2i) {
    const int j = blockIdx.x * 256 + threadIdx.x;
    float s = 0.f;
    for (int d = 0; d < DIM; d++) s += m3[(size_t)d * OPD * HID + j];
    h2i[j] = DIM - (int)(s + 0.5f);
}

// Counting sort (layer1 by h1, layer2 by h2) + per-tile K bounds. Only small
// arrays touched -> fast despite single block. Skipped K-region is exact
// zeros -> bit-identical results.
__global__ __launch_bounds__(1024) void sort_kernel(
    const int* __restrict__ h1i, const int* __restrict__ h2i,
    int* __restrict__ perm1, int* __restrict__ perm2,
    int* __restrict__ h1sv, int* __restrict__ h2sv,
    int* __restrict__ klim1, int* __restrict__ klim2, int* __restrict__ klim3)
{
    __shared__ int hist[128];
    __shared__ int h1s[1024], h2s[1024];
    const int t = threadIdx.x;
    const int h1v = h1i[t], h2v = h2i[t];

    if (t < 128) hist[t] = 0;
    __syncthreads();
    atomicAdd(&hist[h1v], 1);
    __syncthreads();
    if (t == 0) { int a = 0; for (int b = 0; b < 128; b++) { int c = hist[b]; hist[b] = a; a += c; } }
    __syncthreads();
    int r = atomicAdd(&hist[h1v], 1);
    perm1[r] = t; h1s[r] = h1v; h1sv[r] = h1v;
    __syncthreads();
    if (t < 128) hist[t] = 0;
    __syncthreads();
    atomicAdd(&hist[h2v], 1);
    __syncthreads();
    if (t == 0) { int a = 0; for (int b = 0; b < 128; b++) { int c = hist[b]; hist[b] = a; a += c; } }
    __syncthreads();
    r = atomicAdd(&hist[h2v], 1);
    perm2[r] = t; h2s[r] = h2v; h2sv[r] = h2v;
    __syncthreads();

    if (t < 8) {
        klim1[t] = ((h1s[t * 128 + 127] + 63) >> 6) << 6;
        int mh = h2s[t * 128 + 127];
        int c = 0;
        for (int j = 0; j < 1024; j++) c += (h1s[j] <= mh) ? 1 : 0;
        klim2[t] = ((c + 63) >> 6) << 6;
    }
    if (t < 26) {
        int dmax = t * 5 + 4; if (dmax > 127) dmax = 127;
        int c = 0;
        for (int j = 0; j < 1024; j++) c += (h2s[j] <= dmax) ? 1 : 0;
        klim3[t] = ((c + 63) >> 6) << 6;
    }
}

// w1p[hp,col] = W1[perm1[hp],col] * (col < h1sv[hp]); b1p[hp]=b1[perm1[hp]]
__global__ void w1_perm_kernel(const float* __restrict__ W1,
                               const float* __restrict__ b1,
                               const int* __restrict__ perm1,
                               const int* __restrict__ h1sv,
                               __hip_bfloat16* __restrict__ w1p,
                               float* __restrict__ b1p) {
    int i = blockIdx.x * blockDim.x + threadIdx.x;   // HID*DIM
    int hp = i >> 7, col = i & 127;
    int src = perm1[hp];
    float v = (col < h1sv[hp]) ? W1[src * DIM + col] : 0.f;
    w1p[i] = __float2bfloat16(v);
    if (col == 0) b1p[hp] = b1[src];
}

// w2p[ip,jp] = W2[perm2[ip],perm1[jp]] * (h1sv[jp] <= h2sv[ip]).
// One block per output row: source row staged in LDS (coalesced), gather in LDS.
__global__ __launch_bounds__(256) void w2_perm_kernel(
    const float* __restrict__ W2, const float* __restrict__ b2,
    const int* __restrict__ perm1, const int* __restrict__ perm2,
    const int* __restrict__ h1sv, const int* __restrict__ h2sv,
    __hip_bfloat16* __restrict__ w2p, float* __restrict__ b2p)
{
    __shared__ float row[HID];
    const int ip = blockIdx.x, t = threadIdx.x;
    const int si = perm2[ip];
    const int h2v = h2sv[ip];
    #pragma unroll
    for (int q = 0; q < 4; q++) row[q * 256 + t] = W2[(size_t)si * HID + q * 256 + t];
    __syncthreads();
    #pragma unroll
    for (int q = 0; q < 4; q++) {
        const int jp = q * 256 + t;
        float v = (h1sv[jp] <= h2v) ? row[perm1[jp]] : 0.f;
        w2p[(size_t)ip * HID + jp] = __float2bfloat16(v);
    }
    if (t == 0) b2p[ip] = b2[si];
}

// w3p[c,kk] = W3[t*125+s, perm2[kk]] * (h2sv[kk] <= d), c=t*128+s (s<125), d=(t*125+s)/25
__global__ __launch_bounds__(256) void w3_perm_kernel(
    const float* __restrict__ W3,
    const int* __restrict__ perm2, const int* __restrict__ h2sv,
    __hip_bfloat16* __restrict__ w3p)
{
    __shared__ float row[HID];
    const int c = blockIdx.x, t = threadIdx.x;
    const int s = c & 127, t3 = c >> 7;
    if (s >= 125) {
        #pragma unroll
        for (int q = 0; q < 4; q++)
            w3p[(size_t)c * HID + q * 256 + t] = __float2bfloat16(0.f);
        return;
    }
    const int srcrow = t3 * 125 + s;
    const int d = srcrow / 25;
    #pragma unroll
    for (int q = 0; q < 4; q++) row[q * 256 + t] = W3[(size_t)srcrow * HID + q * 256 + t];
    __syncthreads();
    #pragma unroll
    for (int q = 0; q < 4; q++) {
        const int kk = q * 256 + t;
        float v = (h2sv[kk] <= d) ? row[perm2[kk]] : 0.f;
        w3p[(size_t)c * HID + kk] = __float2bfloat16(v);
    }
}

// ---------------------------------------------------------------- spline eval
// p[0..7]=uw, p[8..15]=uh, p[16..24]=ud. Verified rounds 2-7.
__device__ __forceinline__ void spline_eval(const float* __restrict__ p,
                                            float xv, float& yout, float& lout) {
    float cw[NK + 1], ch[NK + 1];
    {
        float mx = p[0];
        #pragma unroll
        for (int j = 1; j < NK; j++) mx = fmaxf(mx, p[j]);
        float e[NK], s = 0.f;
        #pragma unroll
        for (int j = 0; j < NK; j++) { e[j] = expf(p[j] - mx); s += e[j]; }
        const float inv = 1.f / s;
        cw[0] = 0.f;
        #pragma unroll
        for (int j = 0; j < NK; j++) cw[j + 1] = cw[j] + (0.001f + 0.992f * e[j] * inv);
    }
    {
        float mx = p[8];
        #pragma unroll
        for (int j = 1; j < NK; j++) mx = fmaxf(mx, p[8 + j]);
        float e[NK], s = 0.f;
        #pragma unroll
        for (int j = 0; j < NK; j++) { e[j] = expf(p[8 + j] - mx); s += e[j]; }
        const float inv = 1.f / s;
        ch[0] = 0.f;
        #pragma unroll
        for (int j = 0; j < NK; j++) ch[j + 1] = ch[j] + (0.001f + 0.992f * e[j] * inv);
    }
    const float icw = 1.f / fmaxf(cw[NK], 1e-12f);
    const float ich = 1.f / fmaxf(ch[NK], 1e-12f);

    const bool inside = (xv >= -3.f) && (xv <= 3.f);
    float xs = (xv + 3.f) * (1.f / 6.f);
    xs = fminf(fmaxf(xs, 0.f), 1.f);
    const float xsc = xs * cw[NK];

    float xk = 0.f, wk = cw[1], yk = 0.f, hk = ch[1];
    float uda = p[16], udb = p[17];
    #pragma unroll
    for (int j = 1; j < NK; j++) {
        const bool c = (xsc >= cw[j]);
        xk  = c ? cw[j] : xk;
        wk  = c ? (cw[j + 1] - cw[j]) : wk;
        yk  = c ? ch[j] : yk;
        hk  = c ? (ch[j + 1] - ch[j]) : hk;
        uda = c ? p[16 + j] : uda;
        udb = c ? p[17 + j] : udb;
    }
    xk *= icw; wk *= icw;
    yk *= ich; hk *= ich;

    const float dk  = 0.001f + ((uda > 20.f) ? uda : log1pf(expf(uda)));
    const float dk1 = 0.001f + ((udb > 20.f) ? udb : log1pf(expf(udb)));

    float t = (xs - xk) / (wk + 1e-12f);
    t = fminf(fmaxf(t, 0.f), 1.f);
    const float a   = (hk + 1e-12f) / (wk + 1e-12f);
    const float omt = 1.f - t;
    const float tt1 = t * omt;
    const float num = a * t * t + dk * tt1;
    const float den = a + (dk + dk1 - 2.f * a) * tt1;
    const float s   = num / (den + 1e-12f);
    const float y   = (yk + hk * s) * 6.f - 3.f;
    const float dnum = a * a * (dk1 * t * t + 2.f * a * tt1 + dk * omt * omt);
    const float dydx = dnum / (den * den + 1e-12f);

    yout = inside ? y : xv;
    lout = inside ? logf(fmaxf(dydx, 1e-12f)) : 0.f;
}

// ---------------------------------------------------------------- GEMM (1,2)
// C[M,N] = A[M,K] * Bw[N,K]^T + bias, silu -> bf16. Per-tile K bound klim;
// long-K tiles scheduled first (reversed bn) to shrink the tail.
__global__ __launch_bounds__(256) void gemm_bt_kernel(
    const unsigned short* __restrict__ A,
    const unsigned short* __restrict__ Bw,
    const float* __restrict__ bias,
    const int* __restrict__ klim,
    __hip_bfloat16* __restrict__ Cout,
    int M, int N, int Kd)
{
    constexpr int BM = 128, BN = 128, BK = 64;
    __shared__ unsigned short As[BM * BK];
    __shared__ unsigned short Bs[BN * BK];

    const int bid = blockIdx.y * gridDim.x + blockIdx.x;
    const int GY  = (gridDim.y >= 16) ? 16 : gridDim.y;
    const int per_group = gridDim.x * GY;
    const int g  = bid / per_group;
    const int rr = bid % per_group;
    const int bn = (gridDim.x - 1 - rr / GY) * BN;    // long-K (high bn) first
    const int bm = (g * GY + (rr % GY)) * BM;
    const int Klim = klim[bn >> 7];

    const int t    = threadIdx.x;
    const int lane = t & 63;
    const int w    = t >> 6;
    const int wr   = (w >> 1) * 64;
    const int wc   = (w & 1) * 64;
    const int lr   = lane & 15;
    const int quad = lane >> 4;
    const int lxor = lr & 7;

    floatx4 acc[4][4] = {};

    const int lrow = lane >> 3;
    const int lcol = ((lane & 7) ^ lrow) * 8;

    for (int k0 = 0; k0 < Klim; k0 += BK) {
        __syncthreads();
        #pragma unroll
        for (int p = 0; p < 4; p++) {
            const int q = w * 4 + p;
            const int r = q * 8 + lrow;
            async_copy16(&A[(size_t)(bm + r) * Kd + k0 + lcol],
                         &As[q * 512 + lane * 8]);
            async_copy16(&Bw[(size_t)(bn + r) * Kd + k0 + lcol],
                         &Bs[q * 512 + lane * 8]);
        }
        __syncthreads();
        #pragma unroll
        for (int ks = 0; ks < BK; ks += 32) {
            const int cbase = (ks >> 3) + quad;
            const int coff  = (cbase ^ lxor) * 8;
            short8 af[4], bfr[4];
            #pragma unroll
            for (int i = 0; i < 4; i++)
                af[i] = *(const short8*)&As[(wr + i * 16 + lr) * BK + coff];
            #pragma unroll
            for (int j = 0; j < 4; j++)
                bfr[j] = *(const short8*)&Bs[(wc + j * 16 + lr) * BK + coff];
            #pragma unroll
            for (int i = 0; i < 4; i++)
                #pragma unroll
                for (int j = 0; j < 4; j++)
                    acc[i][j] = __builtin_amdgcn_mfma_f32_16x16x32_bf16(
                        af[i], bfr[j], acc[i][j], 0, 0, 0);
        }
    }

    #pragma unroll
    for (int j = 0; j < 4; j++) {
        const int col = bn + wc + j * 16 + lr;
        const float bv = bias[col];
        #pragma unroll
        for (int i = 0; i < 4; i++) {
            const int rowb = bm + wr + i * 16 + quad * 4;
            #pragma unroll
            for (int r = 0; r < 4; r++) {
                float v = acc[i][j][r] + bv;
                v = v / (1.f + expf(-v));
                Cout[(size_t)(rowb + r) * N + col] = __float2bfloat16(v);
            }
        }
    }
}

// ---------------------------------------------------------------- GEMM3+spline
__global__ __launch_bounds__(256) void gemm3_spline_kernel(
    const unsigned short* __restrict__ A,    // h2b M x HID (perm2 col order)
    const unsigned short* __restrict__ Bw,   // w3p NP x HID (perm2 col order)
    const float* __restrict__ b3,            // N3 (original layout)
    const int* __restrict__ klim,            // [26]
    const float* __restrict__ x,             // M x DIM fp32
    float* __restrict__ out,                 // M x DIM
    float* __restrict__ lad,                 // M, pre-zeroed
    int M)
{
    constexpr int BM = 128, BN = 128, BK = 64, Kd = HID;
    constexpr int LSE = 133;                          // epilogue stride
    __shared__ __align__(16) char smem[64 * LSE * 4 + 128 * 4]; // 34,560 B
    unsigned short* As = (unsigned short*)smem;       // 16 KB
    unsigned short* Bs = (unsigned short*)(smem + BM * BK * 2);
    float* eb     = (float*)smem;
    float* ladacc = (float*)(smem + 64 * LSE * 4);    // [128]

    const int bid = blockIdx.y * gridDim.x + blockIdx.x;
    const int GY  = 16;                               // gridDim.y = 128
    const int per_group = gridDim.x * GY;
    const int g  = bid / per_group;
    const int rr = bid % per_group;
    const int tile = 25 - rr / GY;                    // long-K tiles first
    const int bn = tile * BN;
    const int bm = (g * GY + (rr % GY)) * BM;
    const int Klim = klim[tile];

    const int t    = threadIdx.x;
    const int lane = t & 63;
    const int w    = t >> 6;
    const int wr   = (w >> 1) * 64;
    const int wc   = (w & 1) * 64;
    const int lr   = lane & 15;
    const int quad = lane >> 4;
    const int lxor = lr & 7;

    if (t < 128) ladacc[t] = 0.f;

    floatx4 acc[4][4] = {};

    const int lrow = lane >> 3;
    const int lcol = ((lane & 7) ^ lrow) * 8;

    for (int k0 = 0; k0 < Klim; k0 += BK) {
        __syncthreads();
        #pragma unroll
        for (int p = 0; p < 4; p++) {
            const int q = w * 4 + p;
            const int r = q * 8 + lrow;
            async_copy16(&A[(size_t)(bm + r) * Kd + k0 + lcol],
                         &As[q * 512 + lane * 8]);
            async_copy16(&Bw[(size_t)(bn + r) * Kd + k0 + lcol],
                         &Bs[q * 512 + lane * 8]);
        }
        __syncthreads();
        #pragma unroll
        for (int ks = 0; ks < BK; ks += 32) {
            const int cbase = (ks >> 3) + quad;
            const int coff  = (cbase ^ lxor) * 8;
            short8 af[4], bfr[4];
            #pragma unroll
            for (int i = 0; i < 4; i++)
                af[i] = *(const short8*)&As[(wr + i * 16 + lr) * BK + coff];
            #pragma unroll
            for (int j = 0; j < 4; j++)
                bfr[j] = *(const short8*)&Bs[(wc + j * 16 + lr) * BK + coff];
            #pragma unroll
            for (int i = 0; i < 4; i++)
                #pragma unroll
                for (int j = 0; j < 4; j++)
                    acc[i][j] = __builtin_amdgcn_mfma_f32_16x16x32_bf16(
                        af[i], bfr[j], acc[i][j], 0, 0, 0);
        }
    }

    // ---- fused epilogue: two 64-row halves ----
    #pragma unroll 1
    for (int h = 0; h < 2; h++) {
        __syncthreads();
        if ((w >> 1) == h) {
            #pragma unroll
            for (int j = 0; j < 4; j++) {
                const int s = wc + j * 16 + lr;
                const float bv = (s < 125) ? b3[tile * 125 + s] : 0.f;
                #pragma unroll
                for (int i = 0; i < 4; i++) {
                    const int lrw = i * 16 + quad * 4;
                    #pragma unroll
                    for (int r2 = 0; r2 < 4; r2++)
                        eb[(lrw + r2) * LSE + s] = acc[i][j][r2] + bv;
                }
            }
        }
        __syncthreads();
        #pragma unroll 1
        for (int q = t; q < 320; q += 256) {
            const int r  = q / 5;
            const int ds = q % 5;
            const int dim = tile * 5 + ds;
            if (dim < DIM) {
                const float* p = eb + r * LSE + ds * 25;
                const int grow = bm + h * 64 + r;
                const float xv = x[(size_t)grow * DIM + dim];
                float y, l;
                spline_eval(p, xv, y, l);
                out[(size_t)grow * DIM + dim] = y;
                atomicAdd(&ladacc[h * 64 + r], l);
            }
        }
    }
    __syncthreads();
    if (t < 128) atomicAdd(&lad[bm + t], ladacc[t]);
}

// ---------------------------------------------------------------- launch
extern "C" void kernel_launch(void* const* d_in, const int* in_sizes, int n_in,
                              void* d_out, int out_size, void* d_ws, size_t ws_size,
                              hipStream_t stream) {
    const float* x  = (const float*)d_in[0];
    const float* W1 = (const float*)d_in[1];
    const float* b1 = (const float*)d_in[2];
    const float* W2 = (const float*)d_in[3];
    const float* b2 = (const float*)d_in[4];
    const float* W3 = (const float*)d_in[5];
    const float* b3 = (const float*)d_in[6];
    const float* m1 = (const float*)d_in[7];
    const float* m3 = (const float*)d_in[9];

    // workspace: ~81 MB + small arrays
    char* ws = (char*)d_ws;
    const size_t OFF_W1B = 0;
    const size_t OFF_W2B = OFF_W1B + (size_t)HID * DIM * 2;
    const size_t OFF_W3P = OFF_W2B + (size_t)HID * HID * 2;
    const size_t OFF_XB  = OFF_W3P + (size_t)NP * HID * 2;
    const size_t OFF_H1B = OFF_XB  + (size_t)BATCH * DIM * 2;
    const size_t OFF_H2B = OFF_H1B + (size_t)BATCH * HID * 2;
    const size_t OFF_SML = OFF_H2B + (size_t)BATCH * HID * 2;

    __hip_bfloat16* w1p = (__hip_bfloat16*)(ws + OFF_W1B);
    __hip_bfloat16* w2p = (__hip_bfloat16*)(ws + OFF_W2B);
    __hip_bfloat16* w3p = (__hip_bfloat16*)(ws + OFF_W3P);
    __hip_bfloat16* xb  = (__hip_bfloat16*)(ws + OFF_XB);
    __hip_bfloat16* h1b = (__hip_bfloat16*)(ws + OFF_H1B);
    __hip_bfloat16* h2b = (__hip_bfloat16*)(ws + OFF_H2B);

    float* b1p   = (float*)(ws + OFF_SML);
    float* b2p   = b1p + HID;
    int*   h1i   = (int*)(b2p + HID);
    int*   h2i   = h1i + HID;
    int*   perm1 = h2i + HID;
    int*   perm2 = perm1 + HID;
    int*   h1sv  = perm2 + HID;
    int*   h2sv  = h1sv + HID;
    int*   klim1 = h2sv + HID;
    int*   klim2 = klim1 + 8;
    int*   klim3 = klim2 + 8;

    float* out_p = (float*)d_out;
    float* lad_p = out_p + (size_t)BATCH * DIM;

    // prep (all coalesced / LDS-staged; masks recomputed from h-values)
    h1_sum_kernel<<<HID, 128, 0, stream>>>(m1, h1i);
    h2_sum_kernel<<<HID / 256, 256, 0, stream>>>(m3, h2i);
    sort_kernel<<<1, 1024, 0, stream>>>(h1i, h2i, perm1, perm2, h1sv, h2sv,
                                        klim1, klim2, klim3);
    w1_perm_kernel<<<(HID * DIM) / 256, 256, 0, stream>>>(W1, b1, perm1, h1sv,
                                                          w1p, b1p);
    w2_perm_kernel<<<HID, 256, 0, stream>>>(W2, b2, perm1, perm2, h1sv, h2sv,
                                            w2p, b2p);
    w3_perm_kernel<<<NP, 256, 0, stream>>>(W3, perm2, h2sv, w3p);
    cvt_bf16_kernel<<<(BATCH * DIM) / 256, 256, 0, stream>>>(x, xb, BATCH * DIM);
    lad_init_kernel<<<BATCH / 256, 256, 0, stream>>>(lad_p);

    // GEMMs (per-tile K bounds from sorted-mask prefixes)
    gemm_bt_kernel<<<dim3(HID / 128, BATCH / 128), 256, 0, stream>>>(
        (const unsigned short*)xb, (const unsigned short*)w1p, b1p, klim1, h1b,
        BATCH, HID, DIM);
    gemm_bt_kernel<<<dim3(HID / 128, BATCH / 128), 256, 0, stream>>>(
        (const unsigned short*)h1b, (const unsigned short*)w2p, b2p, klim2, h2b,
        BATCH, HID, HID);
    gemm3_spline_kernel<<<dim3(NP / 128, BATCH / 128), 256, 0, stream>>>(
        (const unsigned short*)h2b, (const unsigned short*)w3p, b3, klim3, x,
        out_p, lad_p, BATCH);
}

// Round 9
// 271.109 us; speedup vs baseline: 1.4654x; 1.3254x over previous
//
#include <hip/hip_runtime.h>
#include <hip/hip_bf16.h>

// Problem constants (from reference)
#define BATCH 16384
#define DIM   128
#define HID   1024
#define NK    8
#define OPD   25          // 3*K+1
#define N3    (DIM*OPD)   // 3200
#define NP    3328        // 26 tiles x 128 cols; tile = 5 dims x 25 params + 3 pad

typedef __attribute__((ext_vector_type(8))) short  short8;   // 8 bf16 (4 VGPRs)
typedef __attribute__((ext_vector_type(4))) float  floatx4;  // MFMA C/D frag
typedef unsigned int u32;

// fast-math scalar helpers (single v_exp / v_log / v_rcp; rel err ~1e-6,
// negligible vs bf16-GEMM-dominated tolerance)
__device__ __forceinline__ float fexp(float x) { return __expf(x); }
__device__ __forceinline__ float flog(float x) { return __logf(x); }
__device__ __forceinline__ float fdiv(float a, float b) { return __fdividef(a, b); }

// async global->LDS, 16B per lane. dst = wave-uniform base + lane*16.
__device__ __forceinline__ void async_copy16(const unsigned short* g,
                                             unsigned short* l) {
    __builtin_amdgcn_global_load_lds(
        (const __attribute__((address_space(1))) u32*)g,
        (__attribute__((address_space(3))) u32*)l,
        16, 0, 0);
}

// ---------------------------------------------------------------- prep kernels
// merged: x -> bf16 cast + lad zero-init
__global__ __launch_bounds__(256) void prep_x_lad_kernel(
    const float* __restrict__ x, __hip_bfloat16* __restrict__ xb,
    float* __restrict__ lad) {
    int i = blockIdx.x * 256 + threadIdx.x;
    xb[i] = __float2bfloat16(x[i]);                  // grid covers BATCH*DIM
    if (i < BATCH) lad[i] = 0.f;
}

// merged h1/h2 recovery: blocks [0,HID) do h1 row-reduce; [HID,HID+8) do h2 cols
__global__ __launch_bounds__(128) void hsum_kernel(
    const float* __restrict__ m1, const float* __restrict__ m3,
    int* __restrict__ h1i, int* __restrict__ h2i) {
    const int b = blockIdx.x, t = threadIdx.x;
    if (b < HID) {
        float v = m1[b * DIM + t];
        #pragma unroll
        for (int off = 32; off > 0; off >>= 1) v += __shfl_down(v, off, 64);
        __shared__ float ws[2];
        if ((t & 63) == 0) ws[t >> 6] = v;
        __syncthreads();
        if (t == 0) h1i[b] = (int)(ws[0] + ws[1] + 0.5f);
    } else {
        const int j = (b - HID) * 128 + t;
        float s = 0.f;
        for (int d = 0; d < DIM; d++) s += m3[(size_t)d * OPD * HID + j];
        h2i[j] = DIM - (int)(s + 0.5f);
    }
}

// Counting sort (layer1 by h1, layer2 by h2) + per-tile K bounds. Skipped
// K-region is exact zeros -> bit-identical.
__global__ __launch_bounds__(1024) void sort_kernel(
    const int* __restrict__ h1i, const int* __restrict__ h2i,
    int* __restrict__ perm1, int* __restrict__ perm2,
    int* __restrict__ h1sv, int* __restrict__ h2sv,
    int* __restrict__ klim1, int* __restrict__ klim2, int* __restrict__ klim3)
{
    __shared__ int hist[128];
    __shared__ int h1s[1024], h2s[1024];
    const int t = threadIdx.x;
    const int h1v = h1i[t], h2v = h2i[t];

    if (t < 128) hist[t] = 0;
    __syncthreads();
    atomicAdd(&hist[h1v], 1);
    __syncthreads();
    if (t == 0) { int a = 0; for (int b = 0; b < 128; b++) { int c = hist[b]; hist[b] = a; a += c; } }
    __syncthreads();
    int r = atomicAdd(&hist[h1v], 1);
    perm1[r] = t; h1s[r] = h1v; h1sv[r] = h1v;
    __syncthreads();
    if (t < 128) hist[t] = 0;
    __syncthreads();
    atomicAdd(&hist[h2v], 1);
    __syncthreads();
    if (t == 0) { int a = 0; for (int b = 0; b < 128; b++) { int c = hist[b]; hist[b] = a; a += c; } }
    __syncthreads();
    r = atomicAdd(&hist[h2v], 1);
    perm2[r] = t; h2s[r] = h2v; h2sv[r] = h2v;
    __syncthreads();

    if (t < 8) {
        klim1[t] = ((h1s[t * 128 + 127] + 63) >> 6) << 6;
        int mh = h2s[t * 128 + 127];
        int c = 0;
        for (int j = 0; j < 1024; j++) c += (h1s[j] <= mh) ? 1 : 0;
        klim2[t] = ((c + 63) >> 6) << 6;
    }
    if (t < 26) {
        int dmax = t * 5 + 4; if (dmax > 127) dmax = 127;
        int c = 0;
        for (int j = 0; j < 1024; j++) c += (h2s[j] <= dmax) ? 1 : 0;
        klim3[t] = ((c + 63) >> 6) << 6;
    }
}

// w1p[hp,col] = W1[perm1[hp],col] * (col < h1sv[hp]); b1p[hp]=b1[perm1[hp]]
__global__ void w1_perm_kernel(const float* __restrict__ W1,
                               const float* __restrict__ b1,
                               const int* __restrict__ perm1,
                               const int* __restrict__ h1sv,
                               __hip_bfloat16* __restrict__ w1p,
                               float* __restrict__ b1p) {
    int i = blockIdx.x * blockDim.x + threadIdx.x;   // HID*DIM
    int hp = i >> 7, col = i & 127;
    int src = perm1[hp];
    float v = (col < h1sv[hp]) ? W1[src * DIM + col] : 0.f;
    w1p[i] = __float2bfloat16(v);
    if (col == 0) b1p[hp] = b1[src];
}

// w2p[ip,jp] = W2[perm2[ip],perm1[jp]] * (h1sv[jp] <= h2sv[ip]).
__global__ __launch_bounds__(256) void w2_perm_kernel(
    const float* __restrict__ W2, const float* __restrict__ b2,
    const int* __restrict__ perm1, const int* __restrict__ perm2,
    const int* __restrict__ h1sv, const int* __restrict__ h2sv,
    __hip_bfloat16* __restrict__ w2p, float* __restrict__ b2p)
{
    __shared__ float row[HID];
    const int ip = blockIdx.x, t = threadIdx.x;
    const int si = perm2[ip];
    const int h2v = h2sv[ip];
    #pragma unroll
    for (int q = 0; q < 4; q++) row[q * 256 + t] = W2[(size_t)si * HID + q * 256 + t];
    __syncthreads();
    #pragma unroll
    for (int q = 0; q < 4; q++) {
        const int jp = q * 256 + t;
        float v = (h1sv[jp] <= h2v) ? row[perm1[jp]] : 0.f;
        w2p[(size_t)ip * HID + jp] = __float2bfloat16(v);
    }
    if (t == 0) b2p[ip] = b2[si];
}

// w3p[c,kk] = W3[t*125+s, perm2[kk]] * (h2sv[kk] <= d), c=t*128+s (s<125)
__global__ __launch_bounds__(256) void w3_perm_kernel(
    const float* __restrict__ W3,
    const int* __restrict__ perm2, const int* __restrict__ h2sv,
    __hip_bfloat16* __restrict__ w3p)
{
    __shared__ float row[HID];
    const int c = blockIdx.x, t = threadIdx.x;
    const int s = c & 127, t3 = c >> 7;
    if (s >= 125) {
        #pragma unroll
        for (int q = 0; q < 4; q++)
            w3p[(size_t)c * HID + q * 256 + t] = __float2bfloat16(0.f);
        return;
    }
    const int srcrow = t3 * 125 + s;
    const int d = srcrow / 25;
    #pragma unroll
    for (int q = 0; q < 4; q++) row[q * 256 + t] = W3[(size_t)srcrow * HID + q * 256 + t];
    __syncthreads();
    #pragma unroll
    for (int q = 0; q < 4; q++) {
        const int kk = q * 256 + t;
        float v = (h2sv[kk] <= d) ? row[perm2[kk]] : 0.f;
        w3p[(size_t)c * HID + kk] = __float2bfloat16(v);
    }
}

// ---------------------------------------------------------------- spline eval
// p[0..7]=uw, p[8..15]=uh, p[16..24]=ud. Fast-math transcendentals (round 9);
// math otherwise identical to verified rounds 2-8.
__device__ __forceinline__ void spline_eval(const float* __restrict__ p,
                                            float xv, float& yout, float& lout) {
    float cw[NK + 1], ch[NK + 1];
    {
        float mx = p[0];
        #pragma unroll
        for (int j = 1; j < NK; j++) mx = fmaxf(mx, p[j]);
        float e[NK], s = 0.f;
        #pragma unroll
        for (int j = 0; j < NK; j++) { e[j] = fexp(p[j] - mx); s += e[j]; }
        const float inv = fdiv(1.f, s);
        cw[0] = 0.f;
        #pragma unroll
        for (int j = 0; j < NK; j++) cw[j + 1] = cw[j] + (0.001f + 0.992f * e[j] * inv);
    }
    {
        float mx = p[8];
        #pragma unroll
        for (int j = 1; j < NK; j++) mx = fmaxf(mx, p[8 + j]);
        float e[NK], s = 0.f;
        #pragma unroll
        for (int j = 0; j < NK; j++) { e[j] = fexp(p[8 + j] - mx); s += e[j]; }
        const float inv = fdiv(1.f, s);
        ch[0] = 0.f;
        #pragma unroll
        for (int j = 0; j < NK; j++) ch[j + 1] = ch[j] + (0.001f + 0.992f * e[j] * inv);
    }
    const float icw = fdiv(1.f, fmaxf(cw[NK], 1e-12f));
    const float ich = fdiv(1.f, fmaxf(ch[NK], 1e-12f));

    const bool inside = (xv >= -3.f) && (xv <= 3.f);
    float xs = (xv + 3.f) * (1.f / 6.f);
    xs = fminf(fmaxf(xs, 0.f), 1.f);
    const float xsc = xs * cw[NK];

    float xk = 0.f, wk = cw[1], yk = 0.f, hk = ch[1];
    float uda = p[16], udb = p[17];
    #pragma unroll
    for (int j = 1; j < NK; j++) {
        const bool c = (xsc >= cw[j]);
        xk  = c ? cw[j] : xk;
        wk  = c ? (cw[j + 1] - cw[j]) : wk;
        yk  = c ? ch[j] : yk;
        hk  = c ? (ch[j + 1] - ch[j]) : hk;
        uda = c ? p[16 + j] : uda;
        udb = c ? p[17 + j] : udb;
    }
    xk *= icw; wk *= icw;
    yk *= ich; hk *= ich;

    // softplus on the two selected params only
    const float dk  = 0.001f + ((uda > 20.f) ? uda : flog(1.f + fexp(uda)));
    const float dk1 = 0.001f + ((udb > 20.f) ? udb : flog(1.f + fexp(udb)));

    float t = fdiv(xs - xk, wk + 1e-12f);
    t = fminf(fmaxf(t, 0.f), 1.f);
    const float a   = fdiv(hk + 1e-12f, wk + 1e-12f);
    const float omt = 1.f - t;
    const float tt1 = t * omt;
    const float num = a * t * t + dk * tt1;
    const float den = a + (dk + dk1 - 2.f * a) * tt1;
    const float s   = fdiv(num, den + 1e-12f);
    const float y   = (yk + hk * s) * 6.f - 3.f;
    const float dnum = a * a * (dk1 * t * t + 2.f * a * tt1 + dk * omt * omt);
    const float dydx = fdiv(dnum, den * den + 1e-12f);

    yout = inside ? y : xv;
    lout = inside ? flog(fmaxf(dydx, 1e-12f)) : 0.f;
}

// ---------------------------------------------------------------- GEMM (1,2)
// C[M,N] = A[M,K] * Bw[N,K]^T + bias, silu -> bf16. Per-tile K bound klim;
// long-K tiles first. launch_bounds(256,4): 4 blocks/CU residency target.
__global__ __launch_bounds__(256, 4) void gemm_bt_kernel(
    const unsigned short* __restrict__ A,
    const unsigned short* __restrict__ Bw,
    const float* __restrict__ bias,
    const int* __restrict__ klim,
    __hip_bfloat16* __restrict__ Cout,
    int M, int N, int Kd)
{
    constexpr int BM = 128, BN = 128, BK = 64;
    __shared__ unsigned short As[BM * BK];
    __shared__ unsigned short Bs[BN * BK];

    const int bid = blockIdx.y * gridDim.x + blockIdx.x;
    const int GY  = (gridDim.y >= 16) ? 16 : gridDim.y;
    const int per_group = gridDim.x * GY;
    const int g  = bid / per_group;
    const int rr = bid % per_group;
    const int bn = (gridDim.x - 1 - rr / GY) * BN;    // long-K (high bn) first
    const int bm = (g * GY + (rr % GY)) * BM;
    const int Klim = klim[bn >> 7];

    const int t    = threadIdx.x;
    const int lane = t & 63;
    const int w    = t >> 6;
    const int wr   = (w >> 1) * 64;
    const int wc   = (w & 1) * 64;
    const int lr   = lane & 15;
    const int quad = lane >> 4;
    const int lxor = lr & 7;

    floatx4 acc[4][4] = {};

    const int lrow = lane >> 3;
    const int lcol = ((lane & 7) ^ lrow) * 8;

    for (int k0 = 0; k0 < Klim; k0 += BK) {
        __syncthreads();
        #pragma unroll
        for (int p = 0; p < 4; p++) {
            const int q = w * 4 + p;
            const int r = q * 8 + lrow;
            async_copy16(&A[(size_t)(bm + r) * Kd + k0 + lcol],
                         &As[q * 512 + lane * 8]);
            async_copy16(&Bw[(size_t)(bn + r) * Kd + k0 + lcol],
                         &Bs[q * 512 + lane * 8]);
        }
        __syncthreads();
        #pragma unroll
        for (int ks = 0; ks < BK; ks += 32) {
            const int cbase = (ks >> 3) + quad;
            const int coff  = (cbase ^ lxor) * 8;
            short8 af[4], bfr[4];
            #pragma unroll
            for (int i = 0; i < 4; i++)
                af[i] = *(const short8*)&As[(wr + i * 16 + lr) * BK + coff];
            #pragma unroll
            for (int j = 0; j < 4; j++)
                bfr[j] = *(const short8*)&Bs[(wc + j * 16 + lr) * BK + coff];
            #pragma unroll
            for (int i = 0; i < 4; i++)
                #pragma unroll
                for (int j = 0; j < 4; j++)
                    acc[i][j] = __builtin_amdgcn_mfma_f32_16x16x32_bf16(
                        af[i], bfr[j], acc[i][j], 0, 0, 0);
        }
    }

    #pragma unroll
    for (int j = 0; j < 4; j++) {
        const int col = bn + wc + j * 16 + lr;
        const float bv = bias[col];
        #pragma unroll
        for (int i = 0; i < 4; i++) {
            const int rowb = bm + wr + i * 16 + quad * 4;
            #pragma unroll
            for (int r = 0; r < 4; r++) {
                float v = acc[i][j][r] + bv;
                v = v * fdiv(1.f, 1.f + fexp(-v));    // fast silu
                Cout[(size_t)(rowb + r) * N + col] = __float2bfloat16(v);
            }
        }
    }
}

// ---------------------------------------------------------------- GEMM3+spline
__global__ __launch_bounds__(256, 4) void gemm3_spline_kernel(
    const unsigned short* __restrict__ A,    // h2b M x HID (perm2 col order)
    const unsigned short* __restrict__ Bw,   // w3p NP x HID (perm2 col order)
    const float* __restrict__ b3,            // N3 (original layout)
    const int* __restrict__ klim,            // [26]
    const float* __restrict__ x,             // M x DIM fp32
    float* __restrict__ out,                 // M x DIM
    float* __restrict__ lad,                 // M, pre-zeroed
    int M)
{
    constexpr int BM = 128, BN = 128, BK = 64, Kd = HID;
    constexpr int LSE = 133;                          // epilogue stride
    __shared__ __align__(16) char smem[64 * LSE * 4 + 128 * 4]; // 34,560 B
    unsigned short* As = (unsigned short*)smem;       // 16 KB
    unsigned short* Bs = (unsigned short*)(smem + BM * BK * 2);
    float* eb     = (float*)smem;
    float* ladacc = (float*)(smem + 64 * LSE * 4);    // [128]

    const int bid = blockIdx.y * gridDim.x + blockIdx.x;
    const int GY  = 16;                               // gridDim.y = 128
    const int per_group = gridDim.x * GY;
    const int g  = bid / per_group;
    const int rr = bid % per_group;
    const int tile = 25 - rr / GY;                    // long-K tiles first
    const int bn = tile * BN;
    const int bm = (g * GY + (rr % GY)) * BM;
    const int Klim = klim[tile];

    const int t    = threadIdx.x;
    const int lane = t & 63;
    const int w    = t >> 6;
    const int wr   = (w >> 1) * 64;
    const int wc   = (w & 1) * 64;
    const int lr   = lane & 15;
    const int quad = lane >> 4;
    const int lxor = lr & 7;

    if (t < 128) ladacc[t] = 0.f;

    floatx4 acc[4][4] = {};

    const int lrow = lane >> 3;
    const int lcol = ((lane & 7) ^ lrow) * 8;

    for (int k0 = 0; k0 < Klim; k0 += BK) {
        __syncthreads();
        #pragma unroll
        for (int p = 0; p < 4; p++) {
            const int q = w * 4 + p;
            const int r = q * 8 + lrow;
            async_copy16(&A[(size_t)(bm + r) * Kd + k0 + lcol],
                         &As[q * 512 + lane * 8]);
            async_copy16(&Bw[(size_t)(bn + r) * Kd + k0 + lcol],
                         &Bs[q * 512 + lane * 8]);
        }
        __syncthreads();
        #pragma unroll
        for (int ks = 0; ks < BK; ks += 32) {
            const int cbase = (ks >> 3) + quad;
            const int coff  = (cbase ^ lxor) * 8;
            short8 af[4], bfr[4];
            #pragma unroll
            for (int i = 0; i < 4; i++)
                af[i] = *(const short8*)&As[(wr + i * 16 + lr) * BK + coff];
            #pragma unroll
            for (int j = 0; j < 4; j++)
                bfr[j] = *(const short8*)&Bs[(wc + j * 16 + lr) * BK + coff];
            #pragma unroll
            for (int i = 0; i < 4; i++)
                #pragma unroll
                for (int j = 0; j < 4; j++)
                    acc[i][j] = __builtin_amdgcn_mfma_f32_16x16x32_bf16(
                        af[i], bfr[j], acc[i][j], 0, 0, 0);
        }
    }

    // ---- fused epilogue: two 64-row halves ----
    #pragma unroll 1
    for (int h = 0; h < 2; h++) {
        __syncthreads();
        if ((w >> 1) == h) {
            #pragma unroll
            for (int j = 0; j < 4; j++) {
                const int s = wc + j * 16 + lr;
                const float bv = (s < 125) ? b3[tile * 125 + s] : 0.f;
                #pragma unroll
                for (int i = 0; i < 4; i++) {
                    const int lrw = i * 16 + quad * 4;
                    #pragma unroll
                    for (int r2 = 0; r2 < 4; r2++)
                        eb[(lrw + r2) * LSE + s] = acc[i][j][r2] + bv;
                }
            }
        }
        __syncthreads();
        #pragma unroll 1
        for (int q = t; q < 320; q += 256) {
            const int r  = q / 5;
            const int ds = q % 5;
            const int dim = tile * 5 + ds;
            if (dim < DIM) {
                const float* p = eb + r * LSE + ds * 25;
                const int grow = bm + h * 64 + r;
                const float xv = x[(size_t)grow * DIM + dim];
                float y, l;
                spline_eval(p, xv, y, l);
                out[(size_t)grow * DIM + dim] = y;
                atomicAdd(&ladacc[h * 64 + r], l);
            }
        }
    }
    __syncthreads();
    if (t < 128) atomicAdd(&lad[bm + t], ladacc[t]);
}

// ---------------------------------------------------------------- launch
extern "C" void kernel_launch(void* const* d_in, const int* in_sizes, int n_in,
                              void* d_out, int out_size, void* d_ws, size_t ws_size,
                              hipStream_t stream) {
    const float* x  = (const float*)d_in[0];
    const float* W1 = (const float*)d_in[1];
    const float* b1 = (const float*)d_in[2];
    const float* W2 = (const float*)d_in[3];
    const float* b2 = (const float*)d_in[4];
    const float* W3 = (const float*)d_in[5];
    const float* b3 = (const float*)d_in[6];
    const float* m1 = (const float*)d_in[7];
    const float* m3 = (const float*)d_in[9];

    // workspace: ~81 MB + small arrays
    char* ws = (char*)d_ws;
    const size_t OFF_W1B = 0;
    const size_t OFF_W2B = OFF_W1B + (size_t)HID * DIM * 2;
    const size_t OFF_W3P = OFF_W2B + (size_t)HID * HID * 2;
    const size_t OFF_XB  = OFF_W3P + (size_t)NP * HID * 2;
    const size_t OFF_H1B = OFF_XB  + (size_t)BATCH * DIM * 2;
    const size_t OFF_H2B = OFF_H1B + (size_t)BATCH * HID * 2;
    const size_t OFF_SML = OFF_H2B + (size_t)BATCH * HID * 2;

    __hip_bfloat16* w1p = (__hip_bfloat16*)(ws + OFF_W1B);
    __hip_bfloat16* w2p = (__hip_bfloat16*)(ws + OFF_W2B);
    __hip_bfloat16* w3p = (__hip_bfloat16*)(ws + OFF_W3P);
    __hip_bfloat16* xb  = (__hip_bfloat16*)(ws + OFF_XB);
    __hip_bfloat16* h1b = (__hip_bfloat16*)(ws + OFF_H1B);
    __hip_bfloat16* h2b = (__hip_bfloat16*)(ws + OFF_H2B);

    float* b1p   = (float*)(ws + OFF_SML);
    float* b2p   = b1p + HID;
    int*   h1i   = (int*)(b2p + HID);
    int*   h2i   = h1i + HID;
    int*   perm1 = h2i + HID;
    int*   perm2 = perm1 + HID;
    int*   h1sv  = perm2 + HID;
    int*   h2sv  = h1sv + HID;
    int*   klim1 = h2sv + HID;
    int*   klim2 = klim1 + 8;
    int*   klim3 = klim2 + 8;

    float* out_p = (float*)d_out;
    float* lad_p = out_p + (size_t)BATCH * DIM;

    // prep
    hsum_kernel<<<HID + 8, 128, 0, stream>>>(m1, m3, h1i, h2i);
    sort_kernel<<<1, 1024, 0, stream>>>(h1i, h2i, perm1, perm2, h1sv, h2sv,
                                        klim1, klim2, klim3);
    w1_perm_kernel<<<(HID * DIM) / 256, 256, 0, stream>>>(W1, b1, perm1, h1sv,
                                                          w1p, b1p);
    w2_perm_kernel<<<HID, 256, 0, stream>>>(W2, b2, perm1, perm2, h1sv, h2sv,
                                            w2p, b2p);
    w3_perm_kernel<<<NP, 256, 0, stream>>>(W3, perm2, h2sv, w3p);
    prep_x_lad_kernel<<<(BATCH * DIM) / 256, 256, 0, stream>>>(x, xb, lad_p);

    // GEMMs (per-tile K bounds from sorted-mask prefixes)
    gemm_bt_kernel<<<dim3(HID / 128, BATCH / 128), 256, 0, stream>>>(
        (const unsigned short*)xb, (const unsigned short*)w1p, b1p, klim1, h1b,
        BATCH, HID, DIM);
    gemm_bt_kernel<<<dim3(HID / 128, BATCH / 128), 256, 0, stream>>>(
        (const unsigned short*)h1b, (const unsigned short*)w2p, b2p, klim2, h2b,
        BATCH, HID, HID);
    gemm3_spline_kernel<<<dim3(NP / 128, BATCH / 128), 256, 0, stream>>>(
        (const unsigned short*)h2b, (const unsigned short*)w3p, b3, klim3, x,
        out_p, lad_p, BATCH);
}